// Round 11
// baseline (21.472 us; speedup 1.0000x reference)
//
#include <hip/hip_runtime.h>
#include <hip/hip_fp16.h>

// Problem constants (fixed by the reference)
#define NB   512
#define NP   4950          // NA*(NA-1)/2 pairs
#define NG   2475          // pair-groups (2 pairs, 12 contiguous left floats)
#define NOUT 300
#define LDC  128           // row stride in halfwords per dim-matrix
#define BT   1024

typedef float f4v __attribute__((ext_vector_type(4)));
typedef float f2v __attribute__((ext_vector_type(2)));

// largest i with o(i) = i*(199-i)/2 <= p   (triangular row of pair p)
__device__ __forceinline__ int rowOf(int p) {
    int i = (int)((199.0f - sqrtf((float)(39601 - 8 * p))) * 0.5f);
    while ((i + 1) * (199 - (i + 1)) / 2 <= p) ++i;   // float-rounding guard
    while (i * (199 - i) / 2 > p) --i;
    return i;
}

// granule-2 swizzled halfword offset: word index = (c>>1) ^ s(r)
// row writes conflict-free, transposed col writes <=2-way,
// row-sum reads enumerate exactly the row's 50 words.
__device__ __forceinline__ int a16(int r, int c) {
    return r * LDC + (c ^ (((r >> 1) & 31) << 1));
}

__global__ __launch_bounds__(BT, 8)   // VGPR<=64 -> 2 blocks/CU (LDS 76.8KB x2)
void smartderiv_nt(const float* __restrict__ x,     // [NB][NP]
                   const float* __restrict__ left,  // [NB][NP][6] = [ix iy iz jx jy jz]
                   float* __restrict__ out)         // [NB][NOUT]
{
    __shared__ __half T3[3][100 * LDC];   // 76.8 KB

    const int b   = blockIdx.x;
    const int tid = threadIdx.x;

    // zero diagonals (read but never written by products)
    if (tid < 300) {
        const int d = tid / 100, r = tid - 100 * d;
        T3[d][a16(r, r)] = __float2half(0.0f);
    }

    const float* lb  = left + (size_t)b * (6 * NP);
    const f2v*   xb2 = (const f2v*)(x + (size_t)b * NP);

    // ---- single product/transpose pass: all groups, all 3 dims ----
    // Non-temporal loads: zero-reuse stream, skip L1 allocation.
    for (int g = tid; g < NG; g += BT) {
        const f4v* lp = (const f4v*)(lb + 12 * g);
        const f4v l0 = __builtin_nontemporal_load(lp + 0);   // i0x i0y i0z j0x
        const f4v l1 = __builtin_nontemporal_load(lp + 1);   // j0y j0z i1x i1y
        const f4v l2 = __builtin_nontemporal_load(lp + 2);   // i1z j1x j1y j1z
        const f2v xv = __builtin_nontemporal_load(xb2 + g);

        const int p0 = 2 * g;
        const int i0 = rowOf(p0);
        const int j0 = p0 - i0 * (199 - i0) / 2 + i0 + 1;
        int i1, j1;
        if (j0 < 99) { i1 = i0;     j1 = j0 + 1; }
        else         { i1 = i0 + 1; j1 = i1 + 1; }

        // pair 0
        T3[0][a16(i0, j0)] = __float2half(l0[0] * xv[0]);
        T3[1][a16(i0, j0)] = __float2half(l0[1] * xv[0]);
        T3[2][a16(i0, j0)] = __float2half(l0[2] * xv[0]);
        T3[0][a16(j0, i0)] = __float2half(l0[3] * xv[0]);
        T3[1][a16(j0, i0)] = __float2half(l1[0] * xv[0]);
        T3[2][a16(j0, i0)] = __float2half(l1[1] * xv[0]);
        // pair 1
        T3[0][a16(i1, j1)] = __float2half(l1[2] * xv[1]);
        T3[1][a16(i1, j1)] = __float2half(l1[3] * xv[1]);
        T3[2][a16(i1, j1)] = __float2half(l2[0] * xv[1]);
        T3[0][a16(j1, i1)] = __float2half(l2[1] * xv[1]);
        T3[1][a16(j1, i1)] = __float2half(l2[2] * xv[1]);
        T3[2][a16(j1, i1)] = __float2half(l2[3] * xv[1]);
    }
    __syncthreads();   // the only barrier

    // ---- read phase: 2 lanes per output, 25 half2 words each ----
    if (tid < 600) {
        const int q = tid >> 1;               // output id 0..299
        const int u = tid & 1;
        const int d = q / 100;
        const int r = q - 100 * d;
        const int s = (r >> 1) & 31;
        const __half2* row = (const __half2*)(&T3[d][r * LDC]);

        float acc = 0.0f;
        #pragma unroll
        for (int t = 0; t < 25; ++t) {
            const float2 v = __half22float2(row[(2 * t + u) ^ s]);
            acc += v.x + v.y;
        }
        acc += __shfl_xor(acc, 1);            // lanes 2q, 2q+1 combine
        if (u == 0) {
            out[(size_t)b * NOUT + r * 3 + d] = acc * acc;
        }
    }
}

extern "C" void kernel_launch(void* const* d_in, const int* in_sizes, int n_in,
                              void* d_out, int out_size, void* d_ws, size_t ws_size,
                              hipStream_t stream) {
    // setup_inputs order: x, left, batch_ind, des_ind, scatter_idx
    const float* x    = (const float*)d_in[0];
    const float* left = (const float*)d_in[1];
    float* out = (float*)d_out;

    smartderiv_nt<<<NB, BT, 0, stream>>>(x, left, out);
}

// Round 12
// 17.371 us; speedup vs baseline: 1.2361x; 1.2361x over previous
//
#include <hip/hip_runtime.h>
#include <hip/hip_fp16.h>

// Problem constants (fixed by the reference)
#define NB   512
#define NP   4950          // NA*(NA-1)/2 pairs
#define NG   2475          // pair-groups (2 pairs, 12 contiguous left floats)
#define NOUT 300
#define LDC  128           // row stride in halfwords per dim-matrix
#define BT   1024

// largest i with o(i) = i*(199-i)/2 <= p   (triangular row of pair p)
__device__ __forceinline__ int rowOf(int p) {
    int i = (int)((199.0f - sqrtf((float)(39601 - 8 * p))) * 0.5f);
    while ((i + 1) * (199 - (i + 1)) / 2 <= p) ++i;   // float-rounding guard
    while (i * (199 - i) / 2 > p) --i;
    return i;
}

// granule-2 swizzled halfword offset: word index = (c>>1) ^ s(r)
// row writes conflict-free, transposed col writes <=2-way,
// row-sum reads enumerate exactly the row's 50 words.
__device__ __forceinline__ int a16(int r, int c) {
    return r * LDC + (c ^ (((r >> 1) & 31) << 1));
}

__global__ __launch_bounds__(BT, 8)   // VGPR<=64 -> 2 blocks/CU (LDS 76.8KB x2)
void smartderiv_f16(const float* __restrict__ x,     // [NB][NP]
                    const float* __restrict__ left,  // [NB][NP][6] = [ix iy iz jx jy jz]
                    float* __restrict__ out)         // [NB][NOUT]
{
    __shared__ __half T3[3][100 * LDC];   // 76.8 KB

    const int b   = blockIdx.x;
    const int tid = threadIdx.x;

    // zero diagonals (read but never written by products)
    if (tid < 300) {
        const int d = tid / 100, r = tid - 100 * d;
        T3[d][a16(r, r)] = __float2half(0.0f);
    }

    const float*  lb  = left + (size_t)b * (6 * NP);
    const float2* xb2 = (const float2*)(x + (size_t)b * NP);

    // ---- single product/transpose pass: all groups, all 3 dims ----
    for (int g = tid; g < NG; g += BT) {
        const float4* lp = (const float4*)(lb + 12 * g);
        const float4 l0 = lp[0];          // i0x i0y i0z j0x
        const float4 l1 = lp[1];          // j0y j0z i1x i1y
        const float4 l2 = lp[2];          // i1z j1x j1y j1z
        const float2 xv = xb2[g];

        const int p0 = 2 * g;
        const int i0 = rowOf(p0);
        const int j0 = p0 - i0 * (199 - i0) / 2 + i0 + 1;
        int i1, j1;
        if (j0 < 99) { i1 = i0;     j1 = j0 + 1; }
        else         { i1 = i0 + 1; j1 = i1 + 1; }

        // pair 0
        T3[0][a16(i0, j0)] = __float2half(l0.x * xv.x);
        T3[1][a16(i0, j0)] = __float2half(l0.y * xv.x);
        T3[2][a16(i0, j0)] = __float2half(l0.z * xv.x);
        T3[0][a16(j0, i0)] = __float2half(l0.w * xv.x);
        T3[1][a16(j0, i0)] = __float2half(l1.x * xv.x);
        T3[2][a16(j0, i0)] = __float2half(l1.y * xv.x);
        // pair 1
        T3[0][a16(i1, j1)] = __float2half(l1.z * xv.y);
        T3[1][a16(i1, j1)] = __float2half(l1.w * xv.y);
        T3[2][a16(i1, j1)] = __float2half(l2.x * xv.y);
        T3[0][a16(j1, i1)] = __float2half(l2.y * xv.y);
        T3[1][a16(j1, i1)] = __float2half(l2.z * xv.y);
        T3[2][a16(j1, i1)] = __float2half(l2.w * xv.y);
    }
    __syncthreads();   // the only barrier

    // ---- read phase: 2 lanes per output, 25 half2 words each ----
    if (tid < 600) {
        const int q = tid >> 1;               // output id 0..299
        const int u = tid & 1;
        const int d = q / 100;
        const int r = q - 100 * d;
        const int s = (r >> 1) & 31;
        const __half2* row = (const __half2*)(&T3[d][r * LDC]);

        float acc = 0.0f;
        #pragma unroll
        for (int t = 0; t < 25; ++t) {
            const float2 v = __half22float2(row[(2 * t + u) ^ s]);
            acc += v.x + v.y;
        }
        acc += __shfl_xor(acc, 1);            // lanes 2q, 2q+1 combine
        if (u == 0) {
            out[(size_t)b * NOUT + r * 3 + d] = acc * acc;
        }
    }
}

extern "C" void kernel_launch(void* const* d_in, const int* in_sizes, int n_in,
                              void* d_out, int out_size, void* d_ws, size_t ws_size,
                              hipStream_t stream) {
    // setup_inputs order: x, left, batch_ind, des_ind, scatter_idx
    const float* x    = (const float*)d_in[0];
    const float* left = (const float*)d_in[1];
    float* out = (float*)d_out;

    smartderiv_f16<<<NB, BT, 0, stream>>>(x, left, out);
}